// Round 7
// baseline (219216.895 us; speedup 1.0000x reference)
//
#include <hip/hip_runtime.h>

#define HH    100
#define LSEQ  168
#define STEPS 48
#define NTICK 8066     // L0 at tick t (t<8064), L1 at tick t-1
#define SHP   112      // padded h stride (zeros beyond 100)
#define NSTRM 432      // streamed rows (units 768..1199)

#define WS_BYTES (25 * NSTRM * 16)   // 172,800 B packed stream weights

__device__ __forceinline__ float sigmoidf_(float x) {
    return 1.0f / (1.0f + __expf(-x));
}
__device__ __forceinline__ float tanhf_(float x) {
    return 1.0f - 2.0f / (__expf(2.0f * x) + 1.0f);
}

#define DOT4(acc, w4, h4) acc += (w4).x*(h4).x + (w4).y*(h4).y + (w4).z*(h4).z + (w4).w*(h4).w
#define RED4(x) { x += __shfl_xor(x, 1); x += __shfl_xor(x, 2); }

// Unit u (global gate-row id, 0..1199):
//   u <  400 : Whh0 row u      (input h0) -> L0 gates
//   u <  800 : Wih1 row u-400  (input h0) -> L1 "a"
//   u < 1200 : Whh1 row u-800  (input h1) -> L1 "b"
__device__ __forceinline__ const float* row_ptr(int u, const float* Whh0,
                                                const float* Wih1, const float* Whh1) {
    return (u < 400) ? (Whh0 + u * HH)
         : (u < 800) ? (Wih1 + (u - 400) * HH)
                     : (Whh1 + (u - 800) * HH);
}

// Pack streamed rows (units 768..1199) as ws4[kc][r], r contiguous -> coalesced.
__global__ void prep_kernel(const float* __restrict__ Wih1,
                            const float* __restrict__ Whh1,
                            float* __restrict__ wsT) {
    int idx = blockIdx.x * 256 + threadIdx.x;   // float4 index
    if (idx >= 25 * NSTRM) return;
    int kc = idx / NSTRM, r = idx % NSTRM;
    const float* src = (r < 32) ? (Wih1 + (368 + r) * HH + 4 * kc)
                                : (Whh1 + (r - 32) * HH + 4 * kc);
    *(float4*)&wsT[idx * 4] = *(const float4*)src;
}

// 512 thr = 8 waves = 2 waves/SIMD. Observed backend split: 128 arch + 128 acc
// per thread. Design: <=120 arch (56 weight fl + working set), 112 fl pinned
// into AGPRs ONCE (outside the tick loop; in-loop pins = R4's 281 ms disaster).
template <bool PACKED>
__global__
__attribute__((amdgpu_flat_work_group_size(512, 512), amdgpu_waves_per_eu(2, 2)))
void lstm_kernel(const float* __restrict__ X,     // (512,168)
                 const float* __restrict__ Wih0,  // (400,1)
                 const float* __restrict__ Whh0,  // (400,100)
                 const float* __restrict__ bih0,
                 const float* __restrict__ bhh0,
                 const float* __restrict__ Wih1,  // (400,100)
                 const float* __restrict__ Whh1,  // (400,100)
                 const float* __restrict__ bih1,
                 const float* __restrict__ bhh1,
                 const float* __restrict__ fcw,   // (100)
                 const float* __restrict__ fcb,   // (1)
                 const float* __restrict__ wsT,   // packed stream weights
                 float* __restrict__ out)         // (512,48)
{
    __shared__ __align__(16) float2 G2[1200];   // per-unit gate partial (batchA,batchB)
    __shared__ __align__(16) float  hS[4*SHP];  // [h0 bA][h0 bB][h1 bA][h1 bB], zero-pad
    __shared__ float yS[4];                     // yacc[2], ybuf[2]

    const int t  = threadIdx.x;
    const int s  = t & 3;
    const int v  = t >> 2;
    const int kb = 28 * s;
    const int b0 = blockIdx.x * 2;

    // ---- one-time init ----
    if (t < 4 * SHP) hS[t] = 0.0f;
    if (t < 4) yS[t] = 0.0f;
    const float fcb0 = fcb[0];

    // ---- arch-reg weights: k-window s of rows 6v, 6v+1 (56 floats) ----
    float4 aw0[7], aw1[7];
    {
        const float* r0 = row_ptr(6 * v,     Whh0, Wih1, Whh1);
        const float* r1 = row_ptr(6 * v + 1, Whh0, Wih1, Whh1);
        #pragma unroll
        for (int i = 0; i < 7; ++i) {
            const int k0 = kb + 4 * i;
            if (k0 < HH) { aw0[i] = *(const float4*)(r0 + k0);
                           aw1[i] = *(const float4*)(r1 + k0); }
            else { aw0[i] = make_float4(0.f,0.f,0.f,0.f);
                   aw1[i] = make_float4(0.f,0.f,0.f,0.f); }
        }
    }
    // ---- AGPR weights: k-window s of rows 6v+2..6v+5 (112 floats) ----
    // Load+pin row by row so init-time arch pressure stays low.
    float4 qw[4][7];
    #pragma unroll
    for (int r = 0; r < 4; ++r) {
        const float* rp = row_ptr(6 * v + 2 + r, Whh0, Wih1, Whh1);
        #pragma unroll
        for (int i = 0; i < 7; ++i) {
            const int k0 = kb + 4 * i;
            qw[r][i] = (k0 < HH) ? *(const float4*)(rp + k0)
                                 : make_float4(0.f,0.f,0.f,0.f);
        }
        #pragma unroll
        for (int i = 0; i < 7; ++i)
            asm volatile("" : "+a"(qw[r][i].x), "+a"(qw[r][i].y),
                              "+a"(qw[r][i].z), "+a"(qw[r][i].w));
    }

    // ---- Phase-B constants in registers ----
    int ub = 0, uj = 0;
    float pbb[4] = {0.f,0.f,0.f,0.f}, pwx[4] = {0.f,0.f,0.f,0.f}, fcwr = 0.f;
    if (t < 200) {
        ub = t / 100; uj = t % 100;
        #pragma unroll
        for (int g = 0; g < 4; ++g) {
            pbb[g] = bih0[g * 100 + uj] + bhh0[g * 100 + uj];
            pwx[g] = Wih0[g * 100 + uj];
        }
        fcwr = fcw[uj];
    } else if (t < 400) {
        ub = (t - 200) / 100; uj = (t - 200) % 100;
        #pragma unroll
        for (int g = 0; g < 4; ++g)
            pbb[g] = bih1[g * 100 + uj] + bhh1[g * 100 + uj];
    }
    const float* xrow = X + (b0 + ub) * LSEQ;

    // ---- stream task: row 768+t for t<432 ----
    const bool hasStrm = (t < NSTRM);
    const int  srow = 768 + t;
    const int  shb  = (srow < 800) ? 0 : 2 * SHP;   // h0 for Wih1 rows, h1 for Whh1
    const float* sw  = PACKED ? (wsT + t * 4)
                              : row_ptr(srow, Whh0, Wih1, Whh1);

    float c0 = 0.0f, c1 = 0.0f;

    __syncthreads();

    #pragma unroll 1
    for (int tick = 0; tick < NTICK; ++tick) {
        const bool ydtick = (tick >= 2) && ((tick - 2) % LSEQ == (LSEQ - 1));

        // ================= Phase A =================
        // (1) register rows (6 per (v,s)-group, all input h0), k-window kb.
        {
            float a0A=0.f,a0B=0.f,a1A=0.f,a1B=0.f,a2A=0.f,a2B=0.f;
            float a3A=0.f,a3B=0.f,a4A=0.f,a4B=0.f,a5A=0.f,a5B=0.f;
            #pragma unroll
            for (int i = 0; i < 7; ++i) {
                const float4 hA = *(const float4*)&hS[kb + 4 * i];
                const float4 hB = *(const float4*)&hS[SHP + kb + 4 * i];
                DOT4(a0A, aw0[i], hA);   DOT4(a0B, aw0[i], hB);
                DOT4(a1A, aw1[i], hA);   DOT4(a1B, aw1[i], hB);
                DOT4(a2A, qw[0][i], hA); DOT4(a2B, qw[0][i], hB);
                DOT4(a3A, qw[1][i], hA); DOT4(a3B, qw[1][i], hB);
                DOT4(a4A, qw[2][i], hA); DOT4(a4B, qw[2][i], hB);
                DOT4(a5A, qw[3][i], hA); DOT4(a5B, qw[3][i], hB);
            }
            RED4(a0A); RED4(a0B); RED4(a1A); RED4(a1B);
            RED4(a2A); RED4(a2B); RED4(a3A); RED4(a3B);
            RED4(a4A); RED4(a4B); RED4(a5A); RED4(a5B);
            // lane s writes rows 6v+2s, 6v+2s+1 as one aligned float4 (s<3).
            if (s == 0)      *(float4*)&G2[6*v]     = make_float4(a0A,a0B,a1A,a1B);
            else if (s == 1) *(float4*)&G2[6*v + 2] = make_float4(a2A,a2B,a3A,a3B);
            else if (s == 2) *(float4*)&G2[6*v + 4] = make_float4(a4A,a4B,a5A,a5B);
        }
        // (2) streamed row (units 768..1199), coalesced dwordx4, 2-stage pipeline.
        if (hasStrm) {
            float aA = 0.f, aB = 0.f;
            float4 wnext = PACKED ? *(const float4*)sw : *(const float4*)sw;
            #pragma unroll
            for (int kc = 0; kc < 25; ++kc) {
                const float4 w4 = wnext;
                if (kc < 24)
                    wnext = PACKED ? *(const float4*)(sw + (kc + 1) * (NSTRM * 4))
                                   : *(const float4*)(sw + 4 * (kc + 1));
                const float4 hA = *(const float4*)&hS[shb + 4 * kc];
                const float4 hB = *(const float4*)&hS[shb + SHP + 4 * kc];
                DOT4(aA, w4, hA); DOT4(aB, w4, hB);
            }
            G2[srow] = make_float2(aA, aB);
        }
        // (3) fc dot (once per 168 ticks), reads stable h1.
        if (ydtick && t < 200) {
            atomicAdd(&yS[ub], fcwr * hS[2 * SHP + ub * SHP + uj]);
        }
        __syncthreads();

        // ================= Phase B =================
        if (t < 200) {
            if (tick < 8064) {               // L0, global step = tick
                const int st = tick / LSEQ, p = tick % LSEQ;
                float x;
                if (st == 0)           x = xrow[p];
                else if (p < LSEQ - 1) x = xrow[p + 1];
                else                   x = yS[2 + ub];
                float Gt[4];
                #pragma unroll
                for (int g = 0; g < 4; ++g) {
                    const float2 gp = G2[g * 100 + uj];
                    Gt[g] = pbb[g] + pwx[g] * x + (ub ? gp.y : gp.x);
                }
                c0 = sigmoidf_(Gt[1]) * c0 + sigmoidf_(Gt[0]) * tanhf_(Gt[2]);
                hS[ub * SHP + uj] = sigmoidf_(Gt[3]) * tanhf_(c0);
            }
        } else if (t < 400) {
            if (tick >= 1 && tick <= 8064) { // L1, global step = tick-1
                float Gt[4];
                #pragma unroll
                for (int g = 0; g < 4; ++g) {
                    const float2 ga = G2[400 + g * 100 + uj];
                    const float2 gb = G2[800 + g * 100 + uj];
                    Gt[g] = pbb[g] + (ub ? (ga.y + gb.y) : (ga.x + gb.x));
                }
                c1 = sigmoidf_(Gt[1]) * c1 + sigmoidf_(Gt[0]) * tanhf_(Gt[2]);
                hS[2 * SHP + ub * SHP + uj] = sigmoidf_(Gt[3]) * tanhf_(c1);
            }
        } else if (t == 511) {
            if (ydtick) {
                const int st = (tick - 2) / LSEQ;
                const float y0 = yS[0] + fcb0;
                const float y1 = yS[1] + fcb0;
                yS[2] = y0; yS[3] = y1;
                out[b0 * STEPS + st]       = y0;
                out[(b0 + 1) * STEPS + st] = y1;
                yS[0] = 0.0f; yS[1] = 0.0f;
            }
        }
        __syncthreads();
    }
}

extern "C" void kernel_launch(void* const* d_in, const int* in_sizes, int n_in,
                              void* d_out, int out_size, void* d_ws, size_t ws_size,
                              hipStream_t stream) {
    const float* X    = (const float*)d_in[0];
    const float* Wih0 = (const float*)d_in[1];
    const float* Whh0 = (const float*)d_in[2];
    const float* bih0 = (const float*)d_in[3];
    const float* bhh0 = (const float*)d_in[4];
    const float* Wih1 = (const float*)d_in[5];
    const float* Whh1 = (const float*)d_in[6];
    const float* bih1 = (const float*)d_in[7];
    const float* bhh1 = (const float*)d_in[8];
    const float* fcw  = (const float*)d_in[9];
    const float* fcb  = (const float*)d_in[10];
    float* out = (float*)d_out;
    float* wsT = (float*)d_ws;

    if (ws_size >= (size_t)WS_BYTES) {
        hipLaunchKernelGGL(prep_kernel, dim3((25 * NSTRM + 255) / 256), dim3(256), 0, stream,
                           Wih1, Whh1, wsT);
        hipLaunchKernelGGL(lstm_kernel<true>, dim3(256), dim3(512), 0, stream,
                           X, Wih0, Whh0, bih0, bhh0, Wih1, Whh1, bih1, bhh1,
                           fcw, fcb, wsT, out);
    } else {
        hipLaunchKernelGGL(lstm_kernel<false>, dim3(256), dim3(512), 0, stream,
                           X, Wih0, Whh0, bih0, bhh0, Wih1, Whh1, bih1, bhh1,
                           fcw, fcb, wsT, out);
    }
}

// Round 8
// 214378.296 us; speedup vs baseline: 1.0226x; 1.0226x over previous
//
#include <hip/hip_runtime.h>

#define HH    100
#define LSEQ  168
#define STEPS 48
#define NTICK 8066     // L0 at tick t (t<8064), L1 at tick t-1
#define SHP   112      // padded h stride (zeros beyond 100)
#define NLR   128      // LDS-tier rows (units 768..895)
#define NSTRM 304      // stream-tier rows (units 896..1199 = Whh1 rows 96..399)

__device__ __forceinline__ float sigmoidf_(float x) {
    return 1.0f / (1.0f + __expf(-x));
}
__device__ __forceinline__ float tanhf_(float x) {
    return 1.0f - 2.0f / (__expf(2.0f * x) + 1.0f);
}

#define DOT4(acc, w4, h4) acc += (w4).x*(h4).x + (w4).y*(h4).y + (w4).z*(h4).z + (w4).w*(h4).w
#define RED4(x) { x += __shfl_xor(x, 1); x += __shfl_xor(x, 2); }

// Unit u (gate-row id, 0..1199):
//   u <  400 : Whh0 row u      (input h0) -> L0 gates
//   u <  800 : Wih1 row u-400  (input h0) -> L1 "a"
//   u < 1200 : Whh1 row u-800  (input h1) -> L1 "b"
// Tiers: u<768 regs (R7 scheme: group v=t>>2 owns k-window s=t&3 of rows
// 6v..6v+5: 2 arch + 4 AGPR-pinned); u in [768,896) LDS rows; u>=896 streamed
// straight from Whh1 (d_in memory = L2-cacheable, R2-proven).
__device__ __forceinline__ const float* row_ptr(int u, const float* Whh0,
                                                const float* Wih1, const float* Whh1) {
    return (u < 400) ? (Whh0 + u * HH)
         : (u < 800) ? (Wih1 + (u - 400) * HH)
                     : (Whh1 + (u - 800) * HH);
}

__global__
__attribute__((amdgpu_flat_work_group_size(512, 512), amdgpu_waves_per_eu(2, 2)))
void lstm_kernel(const float* __restrict__ X,     // (512,168)
                 const float* __restrict__ Wih0,  // (400,1)
                 const float* __restrict__ Whh0,  // (400,100)
                 const float* __restrict__ bih0,
                 const float* __restrict__ bhh0,
                 const float* __restrict__ Wih1,  // (400,100)
                 const float* __restrict__ Whh1,  // (400,100)
                 const float* __restrict__ bih1,
                 const float* __restrict__ bhh1,
                 const float* __restrict__ fcw,   // (100)
                 const float* __restrict__ fcb,   // (1)
                 float* __restrict__ out)         // (512,48)
{
    __shared__ __align__(16) float wQ[25 * NLR * 4]; // [kc][row] float4, 51.2 KB
    __shared__ __align__(16) float2 G2[1200];        // per-unit gate (batchA,batchB)
    __shared__ __align__(16) float  hS[4 * SHP];     // [h0A][h0B][h1A][h1B], zero-pad
    __shared__ float yS[4];                          // yacc[2], ybuf[2]

    const int t  = threadIdx.x;
    const int s  = t & 3;
    const int v  = t >> 2;
    const int kb = 28 * s;
    const int b0 = blockIdx.x * 2;

    // ---- one-time init ----
    if (t < 4 * SHP) hS[t] = 0.0f;
    if (t < 4) yS[t] = 0.0f;
    for (int i = t; i < 25 * NLR; i += 512) {        // LDS weight tier fill
        const int kc = i / NLR, r = i % NLR;
        const float* src = (r < 32) ? (Wih1 + (368 + r) * HH + 4 * kc)
                                    : (Whh1 + (r - 32) * HH + 4 * kc);
        *(float4*)&wQ[i * 4] = *(const float4*)src;
    }
    const float fcb0 = fcb[0];

    // ---- arch-reg weights: k-window s of rows 6v, 6v+1 ----
    float4 aw0[7], aw1[7];
    {
        const float* r0 = row_ptr(6 * v,     Whh0, Wih1, Whh1);
        const float* r1 = row_ptr(6 * v + 1, Whh0, Wih1, Whh1);
        #pragma unroll
        for (int i = 0; i < 7; ++i) {
            const int k0 = kb + 4 * i;
            if (k0 < HH) { aw0[i] = *(const float4*)(r0 + k0);
                           aw1[i] = *(const float4*)(r1 + k0); }
            else { aw0[i] = make_float4(0.f,0.f,0.f,0.f);
                   aw1[i] = make_float4(0.f,0.f,0.f,0.f); }
        }
    }
    // ---- AGPR weights: k-window s of rows 6v+2..6v+5 (one-time pins) ----
    float4 qw[4][7];
    #pragma unroll
    for (int r = 0; r < 4; ++r) {
        const float* rp = row_ptr(6 * v + 2 + r, Whh0, Wih1, Whh1);
        #pragma unroll
        for (int i = 0; i < 7; ++i) {
            const int k0 = kb + 4 * i;
            qw[r][i] = (k0 < HH) ? *(const float4*)(rp + k0)
                                 : make_float4(0.f,0.f,0.f,0.f);
        }
        #pragma unroll
        for (int i = 0; i < 7; ++i)
            asm volatile("" : "+a"(qw[r][i].x), "+a"(qw[r][i].y),
                              "+a"(qw[r][i].z), "+a"(qw[r][i].w));
    }

    // ---- Phase-B constants ----
    int ub = 0, uj = 0;
    float pbb[4] = {0.f,0.f,0.f,0.f}, pwx[4] = {0.f,0.f,0.f,0.f}, fcwr = 0.f;
    if (t < 200) {
        ub = t / 100; uj = t % 100;
        #pragma unroll
        for (int g = 0; g < 4; ++g) {
            pbb[g] = bih0[g * 100 + uj] + bhh0[g * 100 + uj];
            pwx[g] = Wih0[g * 100 + uj];
        }
        fcwr = fcw[uj];
    } else if (t < 400) {
        ub = (t - 200) / 100; uj = (t - 200) % 100;
        #pragma unroll
        for (int g = 0; g < 4; ++g)
            pbb[g] = bih1[g * 100 + uj] + bhh1[g * 100 + uj];
    }
    const float* xrow = X + (b0 + ub) * LSEQ;

    // ---- tier setup ----
    const bool hasStrm = (t < NSTRM);
    const float* srow = Whh1 + (96 + t) * HH;        // stream unit 896+t
    const int lhb = (v < 32) ? 0 : 2 * SHP;          // LDS-tier h base (u 768..799 h0)

    float c0 = 0.0f, c1 = 0.0f;

    __syncthreads();

    #pragma unroll 1
    for (int tick = 0; tick < NTICK; ++tick) {
        const bool ydtick = (tick >= 2) && ((tick - 2) % LSEQ == (LSEQ - 1));

        // ================= Phase A =================
        // (0) kick off stream loads (6-deep) so they fly under the FMA block.
        float4 wbuf[6];
        if (hasStrm) {
            #pragma unroll
            for (int i = 0; i < 6; ++i) wbuf[i] = *(const float4*)(srow + 4 * i);
        }
        // (1) register tier: 6 rows x window kb, input h0, both batches.
        {
            float a0A=0.f,a0B=0.f,a1A=0.f,a1B=0.f,a2A=0.f,a2B=0.f;
            float a3A=0.f,a3B=0.f,a4A=0.f,a4B=0.f,a5A=0.f,a5B=0.f;
            #pragma unroll
            for (int i = 0; i < 7; ++i) {
                const float4 hA = *(const float4*)&hS[kb + 4 * i];
                const float4 hB = *(const float4*)&hS[SHP + kb + 4 * i];
                DOT4(a0A, aw0[i], hA);   DOT4(a0B, aw0[i], hB);
                DOT4(a1A, aw1[i], hA);   DOT4(a1B, aw1[i], hB);
                DOT4(a2A, qw[0][i], hA); DOT4(a2B, qw[0][i], hB);
                DOT4(a3A, qw[1][i], hA); DOT4(a3B, qw[1][i], hB);
                DOT4(a4A, qw[2][i], hA); DOT4(a4B, qw[2][i], hB);
                DOT4(a5A, qw[3][i], hA); DOT4(a5B, qw[3][i], hB);
            }
            RED4(a0A); RED4(a0B); RED4(a1A); RED4(a1B);
            RED4(a2A); RED4(a2B); RED4(a3A); RED4(a3B);
            RED4(a4A); RED4(a4B); RED4(a5A); RED4(a5B);
            if (s == 0)      *(float4*)&G2[6*v]     = make_float4(a0A,a0B,a1A,a1B);
            else if (s == 1) *(float4*)&G2[6*v + 2] = make_float4(a2A,a2B,a3A,a3B);
            else if (s == 2) *(float4*)&G2[6*v + 4] = make_float4(a4A,a4B,a5A,a5B);
        }
        // (2) stream tier: full row 896+t, 6-deep pipelined from L2.
        if (hasStrm) {
            float aA = 0.f, aB = 0.f;
            #pragma unroll
            for (int kc = 0; kc < 25; ++kc) {
                const float4 w4 = wbuf[kc % 6];
                if (kc + 6 < 25)
                    wbuf[kc % 6] = *(const float4*)(srow + 4 * (kc + 6));
                const float4 hA = *(const float4*)&hS[2 * SHP + 4 * kc];
                const float4 hB = *(const float4*)&hS[3 * SHP + 4 * kc];
                DOT4(aA, w4, hA); DOT4(aB, w4, hB);
            }
            G2[896 + t] = make_float2(aA, aB);
        }
        // (3) LDS tier: row 768+v, window s (s==3 -> 4 chunks), shfl-reduce.
        {
            float aA = 0.f, aB = 0.f;
            #pragma unroll
            for (int i = 0; i < 7; ++i) {
                if (s < 3 || i < 4) {
                    const int kc = s * 7 + i;            // <= 24
                    const float4 w4 = *(const float4*)&wQ[(kc * NLR + v) * 4];
                    const float4 hA = *(const float4*)&hS[lhb + kb + 4 * i];
                    const float4 hB = *(const float4*)&hS[lhb + SHP + kb + 4 * i];
                    DOT4(aA, w4, hA); DOT4(aB, w4, hB);
                }
            }
            RED4(aA); RED4(aB);
            if (s == 0) G2[768 + v] = make_float2(aA, aB);
        }
        // (4) fc dot (once per 168 ticks), reads stable h1.
        if (ydtick && t < 200) {
            atomicAdd(&yS[ub], fcwr * hS[2 * SHP + ub * SHP + uj]);
        }
        __syncthreads();

        // ================= Phase B =================
        if (t < 200) {
            if (tick < 8064) {               // L0, global step = tick
                const int st = tick / LSEQ, p = tick % LSEQ;
                float x;
                if (st == 0)           x = xrow[p];
                else if (p < LSEQ - 1) x = xrow[p + 1];
                else                   x = yS[2 + ub];
                float Gt[4];
                #pragma unroll
                for (int g = 0; g < 4; ++g) {
                    const float2 gp = G2[g * 100 + uj];
                    Gt[g] = pbb[g] + pwx[g] * x + (ub ? gp.y : gp.x);
                }
                c0 = sigmoidf_(Gt[1]) * c0 + sigmoidf_(Gt[0]) * tanhf_(Gt[2]);
                hS[ub * SHP + uj] = sigmoidf_(Gt[3]) * tanhf_(c0);
            }
        } else if (t < 400) {
            if (tick >= 1 && tick <= 8064) { // L1, global step = tick-1
                float Gt[4];
                #pragma unroll
                for (int g = 0; g < 4; ++g) {
                    const float2 ga = G2[400 + g * 100 + uj];
                    const float2 gb = G2[800 + g * 100 + uj];
                    Gt[g] = pbb[g] + (ub ? (ga.y + gb.y) : (ga.x + gb.x));
                }
                c1 = sigmoidf_(Gt[1]) * c1 + sigmoidf_(Gt[0]) * tanhf_(Gt[2]);
                hS[2 * SHP + ub * SHP + uj] = sigmoidf_(Gt[3]) * tanhf_(c1);
            }
        } else if (t == 511) {
            if (ydtick) {
                const int st = (tick - 2) / LSEQ;
                const float y0 = yS[0] + fcb0;
                const float y1 = yS[1] + fcb0;
                yS[2] = y0; yS[3] = y1;
                out[b0 * STEPS + st]       = y0;
                out[(b0 + 1) * STEPS + st] = y1;
                yS[0] = 0.0f; yS[1] = 0.0f;
            }
        }
        __syncthreads();
    }
}

extern "C" void kernel_launch(void* const* d_in, const int* in_sizes, int n_in,
                              void* d_out, int out_size, void* d_ws, size_t ws_size,
                              hipStream_t stream) {
    const float* X    = (const float*)d_in[0];
    const float* Wih0 = (const float*)d_in[1];
    const float* Whh0 = (const float*)d_in[2];
    const float* bih0 = (const float*)d_in[3];
    const float* bhh0 = (const float*)d_in[4];
    const float* Wih1 = (const float*)d_in[5];
    const float* Whh1 = (const float*)d_in[6];
    const float* bih1 = (const float*)d_in[7];
    const float* bhh1 = (const float*)d_in[8];
    const float* fcw  = (const float*)d_in[9];
    const float* fcb  = (const float*)d_in[10];
    float* out = (float*)d_out;

    hipLaunchKernelGGL(lstm_kernel, dim3(256), dim3(512), 0, stream,
                       X, Wih0, Whh0, bih0, bhh0, Wih1, Whh1, bih1, bhh1,
                       fcw, fcb, out);
}